// Round 10
// baseline (14530.679 us; speedup 1.0000x reference)
//
#include <hip/hip_runtime.h>
#include <hip/hip_cooperative_groups.h>
#include <math.h>

namespace cg = cooperative_groups;

typedef float f4u __attribute__((ext_vector_type(4), aligned(4)));
typedef float nfloat4 __attribute__((ext_vector_type(4), aligned(16)));

__device__ __forceinline__ float softsign(float v) {
    float d = 1.0f + fabsf(v);
    return v * __builtin_amdgcn_rcpf(d);
}
__device__ __forceinline__ void nt_store4(float* p, float a, float b, float c, float d) {
    nfloat4 v; v.x = a; v.y = b; v.z = c; v.w = d;
    __builtin_nontemporal_store(v, (nfloat4*)p);
}
__device__ __forceinline__ int clamp63(int v) { return v < 0 ? 0 : (v > 63 ? 63 : v); }

__device__ __forceinline__ void load_row6(const float* __restrict__ row, int x0, float r[6]) {
    const float4 v = *(const float4*)(row + x0);
    r[0] = row[x0 == 0 ? 0 : x0 - 1];
    r[1] = v.x; r[2] = v.y; r[3] = v.z; r[4] = v.w;
    r[5] = row[x0 == 60 ? 63 : x0 + 4];
}

// -------- first layer: 2 input channels -> 1 channel --------
__global__ __launch_bounds__(256) void conv_first(const float* __restrict__ in0,
                                                  const float* __restrict__ in1,
                                                  float* __restrict__ out,
                                                  const float* __restrict__ w,
                                                  const float* __restrict__ bias) {
    int tid = blockIdx.x * 256 + threadIdx.x;
    int xq = (tid & 15) << 2;
    int y  = (tid >> 4) & 63;
    int z0 = ((tid >> 10) & 15) << 2;
    int b  = tid >> 14;
    const float* base0 = in0 + (size_t)b * 262144;
    const float* base1 = in1 + (size_t)b * 262144;

    float acc[4][4];
    #pragma unroll
    for (int i = 0; i < 4; ++i)
        #pragma unroll
        for (int j = 0; j < 4; ++j) acc[i][j] = 0.0f;

    #pragma unroll
    for (int zi = 0; zi < 6; ++zi) {
        int zin = clamp63(z0 + zi - 1);
        const float* p0 = base0 + zin * 4096;
        const float* p1 = base1 + zin * 4096;
        #pragma unroll
        for (int dy = 0; dy < 3; ++dy) {
            int yin = clamp63(y + dy - 1);
            float r0[6], r1[6];
            load_row6(p0 + yin * 64, xq, r0);
            load_row6(p1 + yin * 64, xq, r1);
            #pragma unroll
            for (int dz = 0; dz < 3; ++dz) {
                int zo = zi - dz;
                if (zo >= 0 && zo < 4) {
                    #pragma unroll
                    for (int dx = 0; dx < 3; ++dx) {
                        float w0v = w[dz * 9 + dy * 3 + dx];
                        float w1v = w[27 + dz * 9 + dy * 3 + dx];
                        #pragma unroll
                        for (int xx = 0; xx < 4; ++xx) {
                            acc[zo][xx] = fmaf(w0v, r0[xx + dx], acc[zo][xx]);
                            acc[zo][xx] = fmaf(w1v, r1[xx + dx], acc[zo][xx]);
                        }
                    }
                }
            }
        }
    }
    float bv = *bias;
    float* obase = out + (size_t)b * 262144 + (size_t)z0 * 4096 + y * 64 + xq;
    #pragma unroll
    for (int zo = 0; zo < 4; ++zo) {
        float4 o;
        o.x = softsign(acc[zo][0] + bv);
        o.y = softsign(acc[zo][1] + bv);
        o.z = softsign(acc[zo][2] + bv);
        o.w = softsign(acc[zo][3] + bv);
        *(float4*)(obase + zo * 4096) = o;
    }
}

// ---- shared tile helpers (R7-verified math) ----
// Tile: 64x * 8y * 4z.  LDS: 6 planes x 10 rows x stride 68 = 16.3 KB.
#define LROW   68
#define LPLANE 680   // 10*68

__device__ __forceinline__ void stage_tile(float* __restrict__ lds,
                                           const float* __restrict__ base,
                                           int y0, int z0, int l, int g) {
    #pragma unroll
    for (int it = 0; it < 4; ++it) {
        int rid = it * 16 + g;
        if (rid < 60) {
            int pa = rid / 10;
            int pr = rid - pa * 10;
            int gz = clamp63(z0 - 1 + pa);
            int gy = clamp63(y0 - 1 + pr);
            const float* grow = base + gz * 4096 + gy * 64;
            float* lrow = &lds[pa * LPLANE + pr * LROW];
            if (l == 0) {
                float4 v = *(const float4*)grow;
                *(float4*)lrow = (float4){v.x, v.x, v.y, v.z};     // clamp(x-1),x0,x1,x2
            } else {
                f4u v = *(const f4u*)(grow + 4 * l - 1);           // x(4l-1)..x(4l+2)
                *(float4*)(lrow + 4 * l) = (float4){v.x, v.y, v.z, v.w};
            }
            if (l == 15) {
                float t63 = grow[63];
                *(float2*)(lrow + 64) = (float2){t63, t63};        // x63, clamp(x64)
            }
        }
    }
}

__device__ __forceinline__ void compute_tile(const float* __restrict__ lds,
                                             float* __restrict__ obase0,   // out + b*262144
                                             int y0, int z0, int l, int g,
                                             const float* __restrict__ wv, float bv) {
    int xq   = l << 2;
    int yloc = g & 7;
    int zh   = g >> 3;

    float acc[2][4];
    #pragma unroll
    for (int i = 0; i < 2; ++i)
        #pragma unroll
        for (int j = 0; j < 4; ++j) acc[i][j] = 0.0f;

    #pragma unroll
    for (int zi = 0; zi < 4; ++zi) {
        const float* pl = &lds[(2 * zh + zi) * LPLANE];
        #pragma unroll
        for (int dy = 0; dy < 3; ++dy) {
            const float* lrow = pl + (yloc + dy) * LROW;
            const float4 v  = *(const float4*)(lrow + xq);
            const float2 v2 = *(const float2*)(lrow + xq + 4);
            float r[6] = {v.x, v.y, v.z, v.w, v2.x, v2.y};
            #pragma unroll
            for (int dz = 0; dz < 3; ++dz) {
                int zo = zi - dz;
                if (zo >= 0 && zo < 2) {
                    #pragma unroll
                    for (int dx = 0; dx < 3; ++dx) {
                        float ww = wv[dz * 9 + dy * 3 + dx];
                        #pragma unroll
                        for (int xx = 0; xx < 4; ++xx)
                            acc[zo][xx] = fmaf(ww, r[xx + dx], acc[zo][xx]);
                    }
                }
            }
        }
    }

    int y = y0 + yloc;
    float* obase = obase0 + (size_t)(z0 + 2 * zh) * 4096 + y * 64 + xq;
    #pragma unroll
    for (int zo = 0; zo < 2; ++zo) {
        float4 o;
        o.x = softsign(acc[zo][0] + bv);
        o.y = softsign(acc[zo][1] + bv);
        o.z = softsign(acc[zo][2] + bv);
        o.w = softsign(acc[zo][3] + bv);
        *(float4*)(obase + zo * 4096) = o;
    }
}

// ---- fallback middle layer (R7, verified): one layer per dispatch, grid 2048 ----
__global__ __launch_bounds__(256) void conv_mid(const float* __restrict__ in,
                                                float* __restrict__ out,
                                                const float* __restrict__ w,
                                                const float* __restrict__ bias) {
    __shared__ float lds[6 * LPLANE];
    int blk = blockIdx.x;
    int y0 = (blk & 7) << 3;
    int z0 = ((blk >> 3) & 15) << 2;
    int b  = blk >> 7;
    int t  = threadIdx.x;
    int l  = t & 15;
    int g  = t >> 4;

    float wv[27];
    #pragma unroll
    for (int i = 0; i < 27; ++i) wv[i] = w[i];
    float bv = *bias;

    stage_tile(lds, in + (size_t)b * 262144, y0, z0, l, g);
    __syncthreads();
    compute_tile(lds, out + (size_t)b * 262144, y0, z0, l, g, wv, bv);
}

// ---- persistent cooperative kernel: all 100 middle layers in one dispatch ----
// Grid 512 x 256 (2 blocks/CU needed; 16.3 KB LDS -> passes even a 64KB/CU occupancy model).
// Block B owns batch b = B&15 and yz tiles (B>>4) + 32k, k=0..3  (XCD-local under %8 dispatch).
__global__ __launch_bounds__(256) void conv_mid_persist(float* b0, float* b1,
                                                        const float* ws_all,
                                                        const float* bs_all) {
    cg::grid_group grid = cg::this_grid();
    __shared__ float lds[6 * LPLANE];
    int t = threadIdx.x;
    int l = t & 15;
    int g = t >> 4;
    int B = blockIdx.x;
    int b   = B & 15;
    int yz0 = B >> 4;          // 0..31

    #pragma unroll 1
    for (int i = 0; i < 100; ++i) {
        const float* src = ((i & 1) ? b1 : b0) + (size_t)b * 262144;
        float*       dst = ((i & 1) ? b0 : b1) + (size_t)b * 262144;
        const float* w = ws_all + i * 27;
        float wv[27];
        #pragma unroll
        for (int k = 0; k < 27; ++k) wv[k] = w[k];
        float bv = bs_all[i];

        #pragma unroll 1
        for (int k = 0; k < 4; ++k) {
            int yz = yz0 + (k << 5);              // 0..127
            int y0 = (yz & 7) << 3;
            int z0 = ((yz >> 3) & 15) << 2;
            stage_tile(lds, src, y0, z0, l, g);
            __syncthreads();
            compute_tile(lds, dst, y0, z0, l, g, wv, bv);
            __syncthreads();
        }

        __threadfence();    // release: drain stores, writeback L2 for cross-XCD visibility
        grid.sync();
        __threadfence();    // acquire: invalidate potentially-stale cached lines
    }
}

// -------- last layer: 1 -> 3 channels + strided downsample outputs --------
__global__ __launch_bounds__(256) void conv_last(const float* __restrict__ in,
                                                 float* __restrict__ out,
                                                 const float* __restrict__ w,
                                                 const float* __restrict__ bias) {
    int tid = blockIdx.x * 256 + threadIdx.x;
    int xq = (tid & 15) << 2;
    int y  = (tid >> 4) & 63;
    int z0 = ((tid >> 10) & 15) << 2;
    int b  = tid >> 14;
    const float* base = in + (size_t)b * 262144;

    float acc[4][3][4];
    #pragma unroll
    for (int i = 0; i < 4; ++i)
        #pragma unroll
        for (int c = 0; c < 3; ++c)
            #pragma unroll
            for (int j = 0; j < 4; ++j) acc[i][c][j] = 0.0f;

    #pragma unroll
    for (int zi = 0; zi < 6; ++zi) {
        int zin = clamp63(z0 + zi - 1);
        const float* plane = base + zin * 4096;
        #pragma unroll
        for (int dy = 0; dy < 3; ++dy) {
            int yin = clamp63(y + dy - 1);
            float r[6];
            load_row6(plane + yin * 64, xq, r);
            #pragma unroll
            for (int dz = 0; dz < 3; ++dz) {
                int zo = zi - dz;
                if (zo >= 0 && zo < 4) {
                    #pragma unroll
                    for (int c = 0; c < 3; ++c) {
                        #pragma unroll
                        for (int dx = 0; dx < 3; ++dx) {
                            float wc = w[c * 27 + dz * 9 + dy * 3 + dx];
                            #pragma unroll
                            for (int xx = 0; xx < 4; ++xx)
                                acc[zo][c][xx] = fmaf(wc, r[xx + dx], acc[zo][c][xx]);
                        }
                    }
                }
            }
        }
    }

    float* r64 = out;
    float* r32 = out + 12582912;
    float* r16 = r32 + 1572864;
    float* r8  = r16 + 196608;

    float vals[4][3][4];
    #pragma unroll
    for (int zo = 0; zo < 4; ++zo)
        #pragma unroll
        for (int c = 0; c < 3; ++c) {
            float bv = bias[c];
            #pragma unroll
            for (int xx = 0; xx < 4; ++xx)
                vals[zo][c][xx] = softsign(acc[zo][c][xx] + bv);
        }

    #pragma unroll
    for (int c = 0; c < 3; ++c) {
        float* cb = r64 + ((size_t)b * 3 + c) * 262144 + (size_t)z0 * 4096 + y * 64 + xq;
        #pragma unroll
        for (int zo = 0; zo < 4; ++zo) {
            nt_store4(cb + zo * 4096,
                      vals[zo][c][0], vals[zo][c][1], vals[zo][c][2], vals[zo][c][3]);
        }
    }
    if ((y & 1) == 0) {
        #pragma unroll
        for (int c = 0; c < 3; ++c) {
            size_t cb = ((size_t)b * 3 + c) * 32768 + (size_t)(y >> 1) * 32;
            #pragma unroll
            for (int zo = 0; zo < 4; zo += 2) {
                size_t zb = cb + (size_t)((z0 + zo) >> 1) * 1024;
                __builtin_nontemporal_store(vals[zo][c][0], r32 + zb + ((xq + 0) >> 1));
                __builtin_nontemporal_store(vals[zo][c][2], r32 + zb + ((xq + 2) >> 1));
            }
        }
    }
    if ((y & 3) == 0) {
        #pragma unroll
        for (int c = 0; c < 3; ++c) {
            __builtin_nontemporal_store(vals[0][c][0],
                r16 + ((size_t)b * 3 + c) * 4096 + (size_t)(z0 >> 2) * 256 + (y >> 2) * 16 + (xq >> 2));
        }
    }
    if ((y & 7) == 0 && (z0 & 7) == 0 && (xq & 7) == 0) {
        #pragma unroll
        for (int c = 0; c < 3; ++c) {
            __builtin_nontemporal_store(vals[0][c][0],
                r8 + ((size_t)b * 3 + c) * 512 + (size_t)(z0 >> 3) * 64 + (y >> 3) * 8 + (xq >> 3));
        }
    }
}

extern "C" void kernel_launch(void* const* d_in, const int* in_sizes, int n_in,
                              void* d_out, int out_size, void* d_ws, size_t ws_size,
                              hipStream_t stream) {
    const float* preop = (const float*)d_in[0];
    const float* intra = (const float*)d_in[1];
    const float* w0    = (const float*)d_in[2];
    const float* b0p   = (const float*)d_in[3];
    const float* wsp   = (const float*)d_in[4];
    const float* bsp   = (const float*)d_in[5];
    const float* wX    = (const float*)d_in[6];
    const float* bX    = (const float*)d_in[7];
    float* out = (float*)d_out;

    float* buf0 = (float*)d_ws;
    float* buf1 = out;

    conv_first<<<dim3(1024), dim3(256), 0, stream>>>(preop, intra, buf0, w0, b0p);

    void* args[4] = { (void*)&buf0, (void*)&buf1, (void*)&wsp, (void*)&bsp };
    hipError_t cerr = hipLaunchCooperativeKernel((void*)conv_mid_persist,
                                                 dim3(512), dim3(256), args, 0, stream);
    if (cerr != hipSuccess) {
        // deterministic fallback: proven 100-dispatch path (R7)
        for (int i = 0; i < 100; ++i) {
            const float* src = (i & 1) ? buf1 : buf0;
            float* dst       = (i & 1) ? buf0 : buf1;
            conv_mid<<<dim3(2048), dim3(256), 0, stream>>>(src, dst, wsp + i * 27, bsp + i);
        }
    }

    // 100 layers: final output in buf0
    conv_last<<<dim3(1024), dim3(256), 0, stream>>>(buf0, out, wX, bX);
}

// Round 11
// 1363.720 us; speedup vs baseline: 10.6552x; 10.6552x over previous
//
#include <hip/hip_runtime.h>
#include <math.h>

typedef float f4u __attribute__((ext_vector_type(4), aligned(4)));
typedef float nfloat4 __attribute__((ext_vector_type(4), aligned(16)));

__device__ __forceinline__ float softsign(float v) {
    float d = 1.0f + fabsf(v);
    return v * __builtin_amdgcn_rcpf(d);
}
__device__ __forceinline__ void nt_store4(float* p, float a, float b, float c, float d) {
    nfloat4 v; v.x = a; v.y = b; v.z = c; v.w = d;
    __builtin_nontemporal_store(v, (nfloat4*)p);
}
__device__ __forceinline__ int clamp63(int v) { return v < 0 ? 0 : (v > 63 ? 63 : v); }

__device__ __forceinline__ void load_row6(const float* __restrict__ row, int x0, float r[6]) {
    const float4 v = *(const float4*)(row + x0);
    r[0] = row[x0 == 0 ? 0 : x0 - 1];
    r[1] = v.x; r[2] = v.y; r[3] = v.z; r[4] = v.w;
    r[5] = row[x0 == 60 ? 63 : x0 + 4];
}

// -------- first layer: 2 input channels -> 1 channel --------
__global__ __launch_bounds__(256) void conv_first(const float* __restrict__ in0,
                                                  const float* __restrict__ in1,
                                                  float* __restrict__ out,
                                                  const float* __restrict__ w,
                                                  const float* __restrict__ bias) {
    int tid = blockIdx.x * 256 + threadIdx.x;
    int xq = (tid & 15) << 2;
    int y  = (tid >> 4) & 63;
    int z0 = ((tid >> 10) & 15) << 2;
    int b  = tid >> 14;
    const float* base0 = in0 + (size_t)b * 262144;
    const float* base1 = in1 + (size_t)b * 262144;

    float acc[4][4];
    #pragma unroll
    for (int i = 0; i < 4; ++i)
        #pragma unroll
        for (int j = 0; j < 4; ++j) acc[i][j] = 0.0f;

    #pragma unroll
    for (int zi = 0; zi < 6; ++zi) {
        int zin = clamp63(z0 + zi - 1);
        const float* p0 = base0 + zin * 4096;
        const float* p1 = base1 + zin * 4096;
        #pragma unroll
        for (int dy = 0; dy < 3; ++dy) {
            int yin = clamp63(y + dy - 1);
            float r0[6], r1[6];
            load_row6(p0 + yin * 64, xq, r0);
            load_row6(p1 + yin * 64, xq, r1);
            #pragma unroll
            for (int dz = 0; dz < 3; ++dz) {
                int zo = zi - dz;
                if (zo >= 0 && zo < 4) {
                    #pragma unroll
                    for (int dx = 0; dx < 3; ++dx) {
                        float w0v = w[dz * 9 + dy * 3 + dx];
                        float w1v = w[27 + dz * 9 + dy * 3 + dx];
                        #pragma unroll
                        for (int xx = 0; xx < 4; ++xx) {
                            acc[zo][xx] = fmaf(w0v, r0[xx + dx], acc[zo][xx]);
                            acc[zo][xx] = fmaf(w1v, r1[xx + dx], acc[zo][xx]);
                        }
                    }
                }
            }
        }
    }
    float bv = *bias;
    float* obase = out + (size_t)b * 262144 + (size_t)z0 * 4096 + y * 64 + xq;
    #pragma unroll
    for (int zo = 0; zo < 4; ++zo) {
        float4 o;
        o.x = softsign(acc[zo][0] + bv);
        o.y = softsign(acc[zo][1] + bv);
        o.z = softsign(acc[zo][2] + bv);
        o.w = softsign(acc[zo][3] + bv);
        *(float4*)(obase + zo * 4096) = o;
    }
}

// ---- tile helpers: 64x * 8y * 4z per block;  LDS 6 planes x 10 rows x 68 = 16.3 KB ----
#define LROW   68
#define LPLANE 680

// MLP-optimized staging: all 8 global loads issued before any LDS write.
// Addresses are clamp-safe even for the tail rows (rid>=60) -- only writes are guarded.
__device__ __forceinline__ void stage_tile(float* __restrict__ lds,
                                           const float* __restrict__ base,
                                           int y0, int z0, int l, int g) {
    int off = (l == 0) ? 0 : (4 * l - 1);
    float* lrows[4];
    f4u mv[4];
    float tv[4];
    #pragma unroll
    for (int it = 0; it < 4; ++it) {
        int rid = it * 16 + g;              // 0..63; rows 60..63 are dummy (load-only)
        int pa = rid / 10;
        int pr = rid - pa * 10;
        const float* grow = base + clamp63(z0 - 1 + pa) * 4096 + clamp63(y0 - 1 + pr) * 64;
        lrows[it] = &lds[pa * LPLANE + pr * LROW];
        mv[it] = *(const f4u*)(grow + off);  // 4 vector loads back-to-back
        tv[it] = grow[63];                   // row tail (used by l==15)
    }
    #pragma unroll
    for (int it = 0; it < 4; ++it) {
        int rid = it * 16 + g;
        if (rid < 60) {
            if (l == 0)
                *(float4*)lrows[it] = (float4){mv[it].x, mv[it].x, mv[it].y, mv[it].z};
            else
                *(float4*)(lrows[it] + 4 * l) = (float4){mv[it].x, mv[it].y, mv[it].z, mv[it].w};
            if (l == 15)
                *(float2*)(lrows[it] + 64) = (float2){tv[it], tv[it]};
        }
    }
}

__device__ __forceinline__ void compute_tile(const float* __restrict__ lds,
                                             float* __restrict__ obase0,   // out + b*262144
                                             int y0, int z0, int l, int g,
                                             const float* __restrict__ wv, float bv) {
    int xq   = l << 2;
    int yloc = g & 7;
    int zh   = g >> 3;

    float acc[2][4];
    #pragma unroll
    for (int i = 0; i < 2; ++i)
        #pragma unroll
        for (int j = 0; j < 4; ++j) acc[i][j] = 0.0f;

    #pragma unroll
    for (int zi = 0; zi < 4; ++zi) {
        const float* pl = &lds[(2 * zh + zi) * LPLANE];
        #pragma unroll
        for (int dy = 0; dy < 3; ++dy) {
            const float* lrow = pl + (yloc + dy) * LROW;
            const float4 v  = *(const float4*)(lrow + xq);
            const float2 v2 = *(const float2*)(lrow + xq + 4);
            float r[6] = {v.x, v.y, v.z, v.w, v2.x, v2.y};
            #pragma unroll
            for (int dz = 0; dz < 3; ++dz) {
                int zo = zi - dz;
                if (zo >= 0 && zo < 2) {
                    #pragma unroll
                    for (int dx = 0; dx < 3; ++dx) {
                        float ww = wv[dz * 9 + dy * 3 + dx];
                        #pragma unroll
                        for (int xx = 0; xx < 4; ++xx)
                            acc[zo][xx] = fmaf(ww, r[xx + dx], acc[zo][xx]);
                    }
                }
            }
        }
    }

    int y = y0 + yloc;
    float* obase = obase0 + (size_t)(z0 + 2 * zh) * 4096 + y * 64 + xq;
    #pragma unroll
    for (int zo = 0; zo < 2; ++zo) {
        float4 o;
        o.x = softsign(acc[zo][0] + bv);
        o.y = softsign(acc[zo][1] + bv);
        o.z = softsign(acc[zo][2] + bv);
        o.w = softsign(acc[zo][3] + bv);
        *(float4*)(obase + zo * 4096) = o;   // normal store: stays in (local-XCD) L2
    }
}

// ---- middle layer: one layer per dispatch, grid 2048, XCD-affine tile mapping ----
// Workgroups dispatch round-robin across the 8 XCDs (xcd = blockIdx % 8 heuristic).
// We bind z-slab to xcd: z0 in {8*xcd, 8*xcd+4}. Same mapping every layer
// => each XCD's 4 MB L2 holds its 2 MB src-slab + 2 MB dst-slab across layers;
// only the z-halo planes (+-1) are fetched from the neighboring XCD.
__global__ __launch_bounds__(256) void conv_mid(const float* __restrict__ in,
                                                float* __restrict__ out,
                                                const float* __restrict__ w,
                                                const float* __restrict__ bias) {
    __shared__ float lds[6 * LPLANE];
    int blk  = blockIdx.x;
    int xcd  = blk & 7;
    int j    = blk >> 3;               // 0..255
    int b    = j & 15;
    int y0   = ((j >> 4) & 7) << 3;    // 0..56
    int zsel = (j >> 7) & 1;
    int z0   = (xcd << 3) + (zsel << 2);  // xcd's slab: z in [8*xcd, 8*xcd+8)

    int t = threadIdx.x;
    int l = t & 15;
    int g = t >> 4;

    float wv[27];
    #pragma unroll
    for (int i = 0; i < 27; ++i) wv[i] = w[i];
    float bv = *bias;

    stage_tile(lds, in + (size_t)b * 262144, y0, z0, l, g);
    __syncthreads();
    compute_tile(lds, out + (size_t)b * 262144, y0, z0, l, g, wv, bv);
}

// -------- last layer: 1 -> 3 channels + strided downsample outputs --------
__global__ __launch_bounds__(256) void conv_last(const float* __restrict__ in,
                                                 float* __restrict__ out,
                                                 const float* __restrict__ w,
                                                 const float* __restrict__ bias) {
    int tid = blockIdx.x * 256 + threadIdx.x;
    int xq = (tid & 15) << 2;
    int y  = (tid >> 4) & 63;
    int z0 = ((tid >> 10) & 15) << 2;
    int b  = tid >> 14;
    const float* base = in + (size_t)b * 262144;

    float acc[4][3][4];
    #pragma unroll
    for (int i = 0; i < 4; ++i)
        #pragma unroll
        for (int c = 0; c < 3; ++c)
            #pragma unroll
            for (int j = 0; j < 4; ++j) acc[i][c][j] = 0.0f;

    #pragma unroll
    for (int zi = 0; zi < 6; ++zi) {
        int zin = clamp63(z0 + zi - 1);
        const float* plane = base + zin * 4096;
        #pragma unroll
        for (int dy = 0; dy < 3; ++dy) {
            int yin = clamp63(y + dy - 1);
            float r[6];
            load_row6(plane + yin * 64, xq, r);
            #pragma unroll
            for (int dz = 0; dz < 3; ++dz) {
                int zo = zi - dz;
                if (zo >= 0 && zo < 4) {
                    #pragma unroll
                    for (int c = 0; c < 3; ++c) {
                        #pragma unroll
                        for (int dx = 0; dx < 3; ++dx) {
                            float wc = w[c * 27 + dz * 9 + dy * 3 + dx];
                            #pragma unroll
                            for (int xx = 0; xx < 4; ++xx)
                                acc[zo][c][xx] = fmaf(wc, r[xx + dx], acc[zo][c][xx]);
                        }
                    }
                }
            }
        }
    }

    float* r64 = out;
    float* r32 = out + 12582912;
    float* r16 = r32 + 1572864;
    float* r8  = r16 + 196608;

    float vals[4][3][4];
    #pragma unroll
    for (int zo = 0; zo < 4; ++zo)
        #pragma unroll
        for (int c = 0; c < 3; ++c) {
            float bv = bias[c];
            #pragma unroll
            for (int xx = 0; xx < 4; ++xx)
                vals[zo][c][xx] = softsign(acc[zo][c][xx] + bv);
        }

    #pragma unroll
    for (int c = 0; c < 3; ++c) {
        float* cb = r64 + ((size_t)b * 3 + c) * 262144 + (size_t)z0 * 4096 + y * 64 + xq;
        #pragma unroll
        for (int zo = 0; zo < 4; ++zo) {
            nt_store4(cb + zo * 4096,
                      vals[zo][c][0], vals[zo][c][1], vals[zo][c][2], vals[zo][c][3]);
        }
    }
    if ((y & 1) == 0) {
        #pragma unroll
        for (int c = 0; c < 3; ++c) {
            size_t cb = ((size_t)b * 3 + c) * 32768 + (size_t)(y >> 1) * 32;
            #pragma unroll
            for (int zo = 0; zo < 4; zo += 2) {
                size_t zb = cb + (size_t)((z0 + zo) >> 1) * 1024;
                __builtin_nontemporal_store(vals[zo][c][0], r32 + zb + ((xq + 0) >> 1));
                __builtin_nontemporal_store(vals[zo][c][2], r32 + zb + ((xq + 2) >> 1));
            }
        }
    }
    if ((y & 3) == 0) {
        #pragma unroll
        for (int c = 0; c < 3; ++c) {
            __builtin_nontemporal_store(vals[0][c][0],
                r16 + ((size_t)b * 3 + c) * 4096 + (size_t)(z0 >> 2) * 256 + (y >> 2) * 16 + (xq >> 2));
        }
    }
    if ((y & 7) == 0 && (z0 & 7) == 0 && (xq & 7) == 0) {
        #pragma unroll
        for (int c = 0; c < 3; ++c) {
            __builtin_nontemporal_store(vals[0][c][0],
                r8 + ((size_t)b * 3 + c) * 512 + (size_t)(z0 >> 3) * 64 + (y >> 3) * 8 + (xq >> 3));
        }
    }
}

extern "C" void kernel_launch(void* const* d_in, const int* in_sizes, int n_in,
                              void* d_out, int out_size, void* d_ws, size_t ws_size,
                              hipStream_t stream) {
    const float* preop = (const float*)d_in[0];
    const float* intra = (const float*)d_in[1];
    const float* w0    = (const float*)d_in[2];
    const float* b0p   = (const float*)d_in[3];
    const float* wsp   = (const float*)d_in[4];
    const float* bsp   = (const float*)d_in[5];
    const float* wX    = (const float*)d_in[6];
    const float* bX    = (const float*)d_in[7];
    float* out = (float*)d_out;

    float* buf0 = (float*)d_ws;
    float* buf1 = out;

    conv_first<<<dim3(1024), dim3(256), 0, stream>>>(preop, intra, buf0, w0, b0p);
    for (int i = 0; i < 100; ++i) {
        const float* src = (i & 1) ? buf1 : buf0;
        float* dst       = (i & 1) ? buf0 : buf1;
        conv_mid<<<dim3(2048), dim3(256), 0, stream>>>(src, dst, wsp + i * 27, bsp + i);
    }
    conv_last<<<dim3(1024), dim3(256), 0, stream>>>(buf0, out, wX, bX);
}

// Round 12
// 1258.119 us; speedup vs baseline: 11.5495x; 1.0839x over previous
//
#include <hip/hip_runtime.h>
#include <math.h>

typedef float f4u __attribute__((ext_vector_type(4), aligned(4)));
typedef float nfloat4 __attribute__((ext_vector_type(4), aligned(16)));

__device__ __forceinline__ float softsign(float v) {
    float d = 1.0f + fabsf(v);
    return v * __builtin_amdgcn_rcpf(d);
}
__device__ __forceinline__ void nt_store4(float* p, float a, float b, float c, float d) {
    nfloat4 v; v.x = a; v.y = b; v.z = c; v.w = d;
    __builtin_nontemporal_store(v, (nfloat4*)p);
}
__device__ __forceinline__ int clamp63(int v) { return v < 0 ? 0 : (v > 63 ? 63 : v); }

__device__ __forceinline__ void load_row6(const float* __restrict__ row, int x0, float r[6]) {
    const float4 v = *(const float4*)(row + x0);
    r[0] = row[x0 == 0 ? 0 : x0 - 1];
    r[1] = v.x; r[2] = v.y; r[3] = v.z; r[4] = v.w;
    r[5] = row[x0 == 60 ? 63 : x0 + 4];
}

// -------- first layer: 2 input channels -> 1 channel --------
__global__ __launch_bounds__(256) void conv_first(const float* __restrict__ in0,
                                                  const float* __restrict__ in1,
                                                  float* __restrict__ out,
                                                  const float* __restrict__ w,
                                                  const float* __restrict__ bias) {
    int tid = blockIdx.x * 256 + threadIdx.x;
    int xq = (tid & 15) << 2;
    int y  = (tid >> 4) & 63;
    int z0 = ((tid >> 10) & 15) << 2;
    int b  = tid >> 14;
    const float* base0 = in0 + (size_t)b * 262144;
    const float* base1 = in1 + (size_t)b * 262144;

    float acc[4][4];
    #pragma unroll
    for (int i = 0; i < 4; ++i)
        #pragma unroll
        for (int j = 0; j < 4; ++j) acc[i][j] = 0.0f;

    #pragma unroll
    for (int zi = 0; zi < 6; ++zi) {
        int zin = clamp63(z0 + zi - 1);
        const float* p0 = base0 + zin * 4096;
        const float* p1 = base1 + zin * 4096;
        #pragma unroll
        for (int dy = 0; dy < 3; ++dy) {
            int yin = clamp63(y + dy - 1);
            float r0[6], r1[6];
            load_row6(p0 + yin * 64, xq, r0);
            load_row6(p1 + yin * 64, xq, r1);
            #pragma unroll
            for (int dz = 0; dz < 3; ++dz) {
                int zo = zi - dz;
                if (zo >= 0 && zo < 4) {
                    #pragma unroll
                    for (int dx = 0; dx < 3; ++dx) {
                        float w0v = w[dz * 9 + dy * 3 + dx];
                        float w1v = w[27 + dz * 9 + dy * 3 + dx];
                        #pragma unroll
                        for (int xx = 0; xx < 4; ++xx) {
                            acc[zo][xx] = fmaf(w0v, r0[xx + dx], acc[zo][xx]);
                            acc[zo][xx] = fmaf(w1v, r1[xx + dx], acc[zo][xx]);
                        }
                    }
                }
            }
        }
    }
    float bv = *bias;
    float* obase = out + (size_t)b * 262144 + (size_t)z0 * 4096 + y * 64 + xq;
    #pragma unroll
    for (int zo = 0; zo < 4; ++zo) {
        float4 o;
        o.x = softsign(acc[zo][0] + bv);
        o.y = softsign(acc[zo][1] + bv);
        o.z = softsign(acc[zo][2] + bv);
        o.w = softsign(acc[zo][3] + bv);
        *(float4*)(obase + zo * 4096) = o;
    }
}

// ---- middle layer: 64x * 16y * 4z per block, 4z*1y*4x per thread ----
// LDS: 6 planes (z0-1..z0+4 clamped) x 18 rows (y0-1..y0+16 clamped) x stride 68 = 29.4 KB.
// Grid 1024 (4 blocks/CU, 16 waves/CU).  XCD-affine: xcd = blk&7 owns z slab [8*xcd, 8*xcd+8).
#define LROW   68
#define LPLANE 1224   // 18*68

__global__ __launch_bounds__(256) void conv_mid(const float* __restrict__ in,
                                                float* __restrict__ out,
                                                const float* __restrict__ w,
                                                const float* __restrict__ bias) {
    __shared__ float lds[6 * LPLANE];

    int blk  = blockIdx.x;
    int xcd  = blk & 7;
    int j    = blk >> 3;               // 0..127
    int b    = j & 15;
    int y0   = ((j >> 4) & 3) << 4;    // 0,16,32,48
    int zsel = (j >> 6) & 1;
    int z0   = (xcd << 3) + (zsel << 2);   // xcd's slab: z in [8*xcd, 8*xcd+8)

    int t = threadIdx.x;
    int l = t & 15;
    int g = t >> 4;

    const float* base = in + (size_t)b * 262144;

    float wv[27];
    #pragma unroll
    for (int i = 0; i < 27; ++i) wv[i] = w[i];
    float bv = *bias;

    // ---- stage 108 rows (6 planes x 18 rows); batched loads, guarded writes ----
    {
        int off = (l == 0) ? 0 : (4 * l - 1);
        float* lrows[7];
        f4u mv[7];
        float tv[7];
        #pragma unroll
        for (int it = 0; it < 7; ++it) {
            int rid = it * 16 + g;               // 0..111 (108..111 dummy, clamp-safe)
            int pa = rid / 18;
            int pr = rid - pa * 18;
            const float* grow = base + clamp63(z0 - 1 + pa) * 4096 + clamp63(y0 - 1 + pr) * 64;
            lrows[it] = &lds[pa * LPLANE + pr * LROW];
            mv[it] = *(const f4u*)(grow + off);
            tv[it] = grow[63];
        }
        #pragma unroll
        for (int it = 0; it < 7; ++it) {
            int rid = it * 16 + g;
            if (rid < 108) {
                if (l == 0)
                    *(float4*)lrows[it] = (float4){mv[it].x, mv[it].x, mv[it].y, mv[it].z};
                else
                    *(float4*)(lrows[it] + 4 * l) = (float4){mv[it].x, mv[it].y, mv[it].z, mv[it].w};
                if (l == 15)
                    *(float2*)(lrows[it] + 64) = (float2){tv[it], tv[it]};
            }
        }
    }
    __syncthreads();

    // ---- compute: 4z x 1y x 4x per thread ----
    int xq   = l << 2;
    int yloc = g;        // 0..15; LDS rows yloc..yloc+2 = y-1,y,y+1

    float acc[4][4];
    #pragma unroll
    for (int i = 0; i < 4; ++i)
        #pragma unroll
        for (int jj = 0; jj < 4; ++jj) acc[i][jj] = 0.0f;

    #pragma unroll
    for (int zi = 0; zi < 6; ++zi) {
        const float* pl = &lds[zi * LPLANE];
        #pragma unroll
        for (int dy = 0; dy < 3; ++dy) {
            const float* lrow = pl + (yloc + dy) * LROW;
            const float4 v  = *(const float4*)(lrow + xq);
            const float2 v2 = *(const float2*)(lrow + xq + 4);
            float r[6] = {v.x, v.y, v.z, v.w, v2.x, v2.y};
            #pragma unroll
            for (int dz = 0; dz < 3; ++dz) {
                int zo = zi - dz;
                if (zo >= 0 && zo < 4) {
                    #pragma unroll
                    for (int dx = 0; dx < 3; ++dx) {
                        float ww = wv[dz * 9 + dy * 3 + dx];
                        #pragma unroll
                        for (int xx = 0; xx < 4; ++xx)
                            acc[zo][xx] = fmaf(ww, r[xx + dx], acc[zo][xx]);
                    }
                }
            }
        }
    }

    int y = y0 + yloc;
    float* obase = out + (size_t)b * 262144 + (size_t)z0 * 4096 + y * 64 + xq;
    #pragma unroll
    for (int zo = 0; zo < 4; ++zo) {
        float4 o;
        o.x = softsign(acc[zo][0] + bv);
        o.y = softsign(acc[zo][1] + bv);
        o.z = softsign(acc[zo][2] + bv);
        o.w = softsign(acc[zo][3] + bv);
        *(float4*)(obase + zo * 4096) = o;   // normal store: stays in local-XCD L2
    }
}

// -------- last layer: 1 -> 3 channels + strided downsample outputs --------
__global__ __launch_bounds__(256) void conv_last(const float* __restrict__ in,
                                                 float* __restrict__ out,
                                                 const float* __restrict__ w,
                                                 const float* __restrict__ bias) {
    int tid = blockIdx.x * 256 + threadIdx.x;
    int xq = (tid & 15) << 2;
    int y  = (tid >> 4) & 63;
    int z0 = ((tid >> 10) & 15) << 2;
    int b  = tid >> 14;
    const float* base = in + (size_t)b * 262144;

    float acc[4][3][4];
    #pragma unroll
    for (int i = 0; i < 4; ++i)
        #pragma unroll
        for (int c = 0; c < 3; ++c)
            #pragma unroll
            for (int j = 0; j < 4; ++j) acc[i][c][j] = 0.0f;

    #pragma unroll
    for (int zi = 0; zi < 6; ++zi) {
        int zin = clamp63(z0 + zi - 1);
        const float* plane = base + zin * 4096;
        #pragma unroll
        for (int dy = 0; dy < 3; ++dy) {
            int yin = clamp63(y + dy - 1);
            float r[6];
            load_row6(plane + yin * 64, xq, r);
            #pragma unroll
            for (int dz = 0; dz < 3; ++dz) {
                int zo = zi - dz;
                if (zo >= 0 && zo < 4) {
                    #pragma unroll
                    for (int c = 0; c < 3; ++c) {
                        #pragma unroll
                        for (int dx = 0; dx < 3; ++dx) {
                            float wc = w[c * 27 + dz * 9 + dy * 3 + dx];
                            #pragma unroll
                            for (int xx = 0; xx < 4; ++xx)
                                acc[zo][c][xx] = fmaf(wc, r[xx + dx], acc[zo][c][xx]);
                        }
                    }
                }
            }
        }
    }

    float* r64 = out;
    float* r32 = out + 12582912;
    float* r16 = r32 + 1572864;
    float* r8  = r16 + 196608;

    float vals[4][3][4];
    #pragma unroll
    for (int zo = 0; zo < 4; ++zo)
        #pragma unroll
        for (int c = 0; c < 3; ++c) {
            float bv = bias[c];
            #pragma unroll
            for (int xx = 0; xx < 4; ++xx)
                vals[zo][c][xx] = softsign(acc[zo][c][xx] + bv);
        }

    #pragma unroll
    for (int c = 0; c < 3; ++c) {
        float* cb = r64 + ((size_t)b * 3 + c) * 262144 + (size_t)z0 * 4096 + y * 64 + xq;
        #pragma unroll
        for (int zo = 0; zo < 4; ++zo) {
            nt_store4(cb + zo * 4096,
                      vals[zo][c][0], vals[zo][c][1], vals[zo][c][2], vals[zo][c][3]);
        }
    }
    if ((y & 1) == 0) {
        #pragma unroll
        for (int c = 0; c < 3; ++c) {
            size_t cb = ((size_t)b * 3 + c) * 32768 + (size_t)(y >> 1) * 32;
            #pragma unroll
            for (int zo = 0; zo < 4; zo += 2) {
                size_t zb = cb + (size_t)((z0 + zo) >> 1) * 1024;
                __builtin_nontemporal_store(vals[zo][c][0], r32 + zb + ((xq + 0) >> 1));
                __builtin_nontemporal_store(vals[zo][c][2], r32 + zb + ((xq + 2) >> 1));
            }
        }
    }
    if ((y & 3) == 0) {
        #pragma unroll
        for (int c = 0; c < 3; ++c) {
            __builtin_nontemporal_store(vals[0][c][0],
                r16 + ((size_t)b * 3 + c) * 4096 + (size_t)(z0 >> 2) * 256 + (y >> 2) * 16 + (xq >> 2));
        }
    }
    if ((y & 7) == 0 && (z0 & 7) == 0 && (xq & 7) == 0) {
        #pragma unroll
        for (int c = 0; c < 3; ++c) {
            __builtin_nontemporal_store(vals[0][c][0],
                r8 + ((size_t)b * 3 + c) * 512 + (size_t)(z0 >> 3) * 64 + (y >> 3) * 8 + (xq >> 3));
        }
    }
}

extern "C" void kernel_launch(void* const* d_in, const int* in_sizes, int n_in,
                              void* d_out, int out_size, void* d_ws, size_t ws_size,
                              hipStream_t stream) {
    const float* preop = (const float*)d_in[0];
    const float* intra = (const float*)d_in[1];
    const float* w0    = (const float*)d_in[2];
    const float* b0p   = (const float*)d_in[3];
    const float* wsp   = (const float*)d_in[4];
    const float* bsp   = (const float*)d_in[5];
    const float* wX    = (const float*)d_in[6];
    const float* bX    = (const float*)d_in[7];
    float* out = (float*)d_out;

    float* buf0 = (float*)d_ws;
    float* buf1 = out;

    conv_first<<<dim3(1024), dim3(256), 0, stream>>>(preop, intra, buf0, w0, b0p);
    for (int i = 0; i < 100; ++i) {
        const float* src = (i & 1) ? buf1 : buf0;
        float* dst       = (i & 1) ? buf0 : buf1;
        conv_mid<<<dim3(1024), dim3(256), 0, stream>>>(src, dst, wsp + i * 27, bsp + i);
    }
    conv_last<<<dim3(1024), dim3(256), 0, stream>>>(buf0, out, wX, bX);
}

// Round 13
// 1161.898 us; speedup vs baseline: 12.5060x; 1.0828x over previous
//
#include <hip/hip_runtime.h>
#include <math.h>

typedef float f4u __attribute__((ext_vector_type(4), aligned(4)));
typedef float nfloat4 __attribute__((ext_vector_type(4), aligned(16)));

__device__ __forceinline__ float softsign(float v) {
    float d = 1.0f + fabsf(v);
    return v * __builtin_amdgcn_rcpf(d);
}
__device__ __forceinline__ void nt_store4(float* p, float a, float b, float c, float d) {
    nfloat4 v; v.x = a; v.y = b; v.z = c; v.w = d;
    __builtin_nontemporal_store(v, (nfloat4*)p);
}
__device__ __forceinline__ int clamp63(int v) { return v < 0 ? 0 : (v > 63 ? 63 : v); }

__device__ __forceinline__ void load_row6(const float* __restrict__ row, int x0, float r[6]) {
    const float4 v = *(const float4*)(row + x0);
    r[0] = row[x0 == 0 ? 0 : x0 - 1];
    r[1] = v.x; r[2] = v.y; r[3] = v.z; r[4] = v.w;
    r[5] = row[x0 == 60 ? 63 : x0 + 4];
}

// -------- first layer: 2 input channels -> 1 channel --------
__global__ __launch_bounds__(256) void conv_first(const float* __restrict__ in0,
                                                  const float* __restrict__ in1,
                                                  float* __restrict__ out,
                                                  const float* __restrict__ w,
                                                  const float* __restrict__ bias) {
    int tid = blockIdx.x * 256 + threadIdx.x;
    int xq = (tid & 15) << 2;
    int y  = (tid >> 4) & 63;
    int z0 = ((tid >> 10) & 15) << 2;
    int b  = tid >> 14;
    const float* base0 = in0 + (size_t)b * 262144;
    const float* base1 = in1 + (size_t)b * 262144;

    float acc[4][4];
    #pragma unroll
    for (int i = 0; i < 4; ++i)
        #pragma unroll
        for (int j = 0; j < 4; ++j) acc[i][j] = 0.0f;

    #pragma unroll
    for (int zi = 0; zi < 6; ++zi) {
        int zin = clamp63(z0 + zi - 1);
        const float* p0 = base0 + zin * 4096;
        const float* p1 = base1 + zin * 4096;
        #pragma unroll
        for (int dy = 0; dy < 3; ++dy) {
            int yin = clamp63(y + dy - 1);
            float r0[6], r1[6];
            load_row6(p0 + yin * 64, xq, r0);
            load_row6(p1 + yin * 64, xq, r1);
            #pragma unroll
            for (int dz = 0; dz < 3; ++dz) {
                int zo = zi - dz;
                if (zo >= 0 && zo < 4) {
                    #pragma unroll
                    for (int dx = 0; dx < 3; ++dx) {
                        float w0v = w[dz * 9 + dy * 3 + dx];
                        float w1v = w[27 + dz * 9 + dy * 3 + dx];
                        #pragma unroll
                        for (int xx = 0; xx < 4; ++xx) {
                            acc[zo][xx] = fmaf(w0v, r0[xx + dx], acc[zo][xx]);
                            acc[zo][xx] = fmaf(w1v, r1[xx + dx], acc[zo][xx]);
                        }
                    }
                }
            }
        }
    }
    float bv = *bias;
    float* obase = out + (size_t)b * 262144 + (size_t)z0 * 4096 + y * 64 + xq;
    #pragma unroll
    for (int zo = 0; zo < 4; ++zo) {
        float4 o;
        o.x = softsign(acc[zo][0] + bv);
        o.y = softsign(acc[zo][1] + bv);
        o.z = softsign(acc[zo][2] + bv);
        o.w = softsign(acc[zo][3] + bv);
        *(float4*)(obase + zo * 4096) = o;
    }
}

// ---- middle layer: 64x * 16y * 8z per block, thread = 8z*1y*4x (32 outputs) ----
// LDS: 10 planes (z0-1..z0+8 clamped) x 18 rows (y0-1..y0+16 clamped) x stride 68 = 49 KB.
// Grid 512 = 8 z-slabs (bound to XCD via blk&7) x 16 batches x 4 y-tiles; 2 blocks/CU.
#define LROW   68
#define LPLANE 1224   // 18*68

__global__ __launch_bounds__(256) void conv_mid(const float* __restrict__ in,
                                                float* __restrict__ out,
                                                const float* __restrict__ w,
                                                const float* __restrict__ bias) {
    __shared__ float lds[10 * LPLANE];

    int blk = blockIdx.x;
    int xcd = blk & 7;
    int j   = blk >> 3;                // 0..63
    int b   = j & 15;
    int y0  = ((j >> 4) & 3) << 4;     // 0,16,32,48
    int z0  = xcd << 3;                // 0,8,...,56 : XCD-affine z-slab

    int t = threadIdx.x;
    int l = t & 15;
    int g = t >> 4;

    const float* base = in + (size_t)b * 262144;

    float wv[27];
    #pragma unroll
    for (int i = 0; i < 27; ++i) wv[i] = w[i];
    float bv = *bias;

    // ---- stage 180 rows (10 planes x 18 rows); batched loads, guarded writes ----
    {
        int off = (l == 0) ? 0 : (4 * l - 1);
        #pragma unroll
        for (int half = 0; half < 2; ++half) {
            float* lrows[6];
            f4u mv[6];
            float tv[6];
            #pragma unroll
            for (int it = 0; it < 6; ++it) {
                int rid = (half * 6 + it) * 16 + g;      // 0..191 (180..191 dummy)
                int pa = rid / 18;
                pa = pa > 9 ? 9 : pa;                     // dummy rows: clamp-safe addr
                int pr = rid - pa * 18;
                pr = pr > 17 ? 17 : pr;
                const float* grow = base + clamp63(z0 - 1 + pa) * 4096 + clamp63(y0 - 1 + pr) * 64;
                lrows[it] = &lds[pa * LPLANE + pr * LROW];
                mv[it] = *(const f4u*)(grow + off);
                tv[it] = grow[63];
            }
            #pragma unroll
            for (int it = 0; it < 6; ++it) {
                int rid = (half * 6 + it) * 16 + g;
                if (rid < 180) {
                    if (l == 0)
                        *(float4*)lrows[it] = (float4){mv[it].x, mv[it].x, mv[it].y, mv[it].z};
                    else
                        *(float4*)(lrows[it] + 4 * l) = (float4){mv[it].x, mv[it].y, mv[it].z, mv[it].w};
                    if (l == 15)
                        *(float2*)(lrows[it] + 64) = (float2){tv[it], tv[it]};
                }
            }
        }
    }
    __syncthreads();

    // ---- compute: 8z x 1y x 4x per thread ----
    int xq   = l << 2;
    int yloc = g;          // 0..15; LDS rows yloc..yloc+2 = y-1,y,y+1

    float acc[8][4];
    #pragma unroll
    for (int i = 0; i < 8; ++i)
        #pragma unroll
        for (int jj = 0; jj < 4; ++jj) acc[i][jj] = 0.0f;

    #pragma unroll
    for (int zi = 0; zi < 10; ++zi) {
        const float* pl = &lds[zi * LPLANE];
        #pragma unroll
        for (int dy = 0; dy < 3; ++dy) {
            const float* lrow = pl + (yloc + dy) * LROW;
            const float4 v  = *(const float4*)(lrow + xq);
            const float2 v2 = *(const float2*)(lrow + xq + 4);
            float r[6] = {v.x, v.y, v.z, v.w, v2.x, v2.y};
            #pragma unroll
            for (int dz = 0; dz < 3; ++dz) {
                int zo = zi - 1 - dz + 1;   // zo = zi - dz, plane zi covers out z offset zi-1-? ...
                zo = zi - dz;               // staged plane pa corresponds to z = z0-1+pa; out zo = pa-1+? 
                // out z index o (0..7) uses planes o..o+2 (pa = o + dz). So o = zi - dz.
                if (zo >= 0 && zo < 8) {
                    #pragma unroll
                    for (int dx = 0; dx < 3; ++dx) {
                        float ww = wv[dz * 9 + dy * 3 + dx];
                        #pragma unroll
                        for (int xx = 0; xx < 4; ++xx)
                            acc[zo][xx] = fmaf(ww, r[xx + dx], acc[zo][xx]);
                    }
                }
            }
        }
    }

    int y = y0 + yloc;
    float* obase = out + (size_t)b * 262144 + (size_t)z0 * 4096 + y * 64 + xq;
    #pragma unroll
    for (int zo = 0; zo < 8; ++zo) {
        float4 o;
        o.x = softsign(acc[zo][0] + bv);
        o.y = softsign(acc[zo][1] + bv);
        o.z = softsign(acc[zo][2] + bv);
        o.w = softsign(acc[zo][3] + bv);
        *(float4*)(obase + zo * 4096) = o;   // normal store: stays in local-XCD L2
    }
}

// -------- last layer: 1 -> 3 channels + strided downsample outputs --------
__global__ __launch_bounds__(256) void conv_last(const float* __restrict__ in,
                                                 float* __restrict__ out,
                                                 const float* __restrict__ w,
                                                 const float* __restrict__ bias) {
    int tid = blockIdx.x * 256 + threadIdx.x;
    int xq = (tid & 15) << 2;
    int y  = (tid >> 4) & 63;
    int z0 = ((tid >> 10) & 15) << 2;
    int b  = tid >> 14;
    const float* base = in + (size_t)b * 262144;

    float acc[4][3][4];
    #pragma unroll
    for (int i = 0; i < 4; ++i)
        #pragma unroll
        for (int c = 0; c < 3; ++c)
            #pragma unroll
            for (int j = 0; j < 4; ++j) acc[i][c][j] = 0.0f;

    #pragma unroll
    for (int zi = 0; zi < 6; ++zi) {
        int zin = clamp63(z0 + zi - 1);
        const float* plane = base + zin * 4096;
        #pragma unroll
        for (int dy = 0; dy < 3; ++dy) {
            int yin = clamp63(y + dy - 1);
            float r[6];
            load_row6(plane + yin * 64, xq, r);
            #pragma unroll
            for (int dz = 0; dz < 3; ++dz) {
                int zo = zi - dz;
                if (zo >= 0 && zo < 4) {
                    #pragma unroll
                    for (int c = 0; c < 3; ++c) {
                        #pragma unroll
                        for (int dx = 0; dx < 3; ++dx) {
                            float wc = w[c * 27 + dz * 9 + dy * 3 + dx];
                            #pragma unroll
                            for (int xx = 0; xx < 4; ++xx)
                                acc[zo][c][xx] = fmaf(wc, r[xx + dx], acc[zo][c][xx]);
                        }
                    }
                }
            }
        }
    }

    float* r64 = out;
    float* r32 = out + 12582912;
    float* r16 = r32 + 1572864;
    float* r8  = r16 + 196608;

    float vals[4][3][4];
    #pragma unroll
    for (int zo = 0; zo < 4; ++zo)
        #pragma unroll
        for (int c = 0; c < 3; ++c) {
            float bv = bias[c];
            #pragma unroll
            for (int xx = 0; xx < 4; ++xx)
                vals[zo][c][xx] = softsign(acc[zo][c][xx] + bv);
        }

    #pragma unroll
    for (int c = 0; c < 3; ++c) {
        float* cb = r64 + ((size_t)b * 3 + c) * 262144 + (size_t)z0 * 4096 + y * 64 + xq;
        #pragma unroll
        for (int zo = 0; zo < 4; ++zo) {
            nt_store4(cb + zo * 4096,
                      vals[zo][c][0], vals[zo][c][1], vals[zo][c][2], vals[zo][c][3]);
        }
    }
    if ((y & 1) == 0) {
        #pragma unroll
        for (int c = 0; c < 3; ++c) {
            size_t cb = ((size_t)b * 3 + c) * 32768 + (size_t)(y >> 1) * 32;
            #pragma unroll
            for (int zo = 0; zo < 4; zo += 2) {
                size_t zb = cb + (size_t)((z0 + zo) >> 1) * 1024;
                __builtin_nontemporal_store(vals[zo][c][0], r32 + zb + ((xq + 0) >> 1));
                __builtin_nontemporal_store(vals[zo][c][2], r32 + zb + ((xq + 2) >> 1));
            }
        }
    }
    if ((y & 3) == 0) {
        #pragma unroll
        for (int c = 0; c < 3; ++c) {
            __builtin_nontemporal_store(vals[0][c][0],
                r16 + ((size_t)b * 3 + c) * 4096 + (size_t)(z0 >> 2) * 256 + (y >> 2) * 16 + (xq >> 2));
        }
    }
    if ((y & 7) == 0 && (z0 & 7) == 0 && (xq & 7) == 0) {
        #pragma unroll
        for (int c = 0; c < 3; ++c) {
            __builtin_nontemporal_store(vals[0][c][0],
                r8 + ((size_t)b * 3 + c) * 512 + (size_t)(z0 >> 3) * 64 + (y >> 3) * 8 + (xq >> 3));
        }
    }
}

extern "C" void kernel_launch(void* const* d_in, const int* in_sizes, int n_in,
                              void* d_out, int out_size, void* d_ws, size_t ws_size,
                              hipStream_t stream) {
    const float* preop = (const float*)d_in[0];
    const float* intra = (const float*)d_in[1];
    const float* w0    = (const float*)d_in[2];
    const float* b0p   = (const float*)d_in[3];
    const float* wsp   = (const float*)d_in[4];
    const float* bsp   = (const float*)d_in[5];
    const float* wX    = (const float*)d_in[6];
    const float* bX    = (const float*)d_in[7];
    float* out = (float*)d_out;

    float* buf0 = (float*)d_ws;
    float* buf1 = out;

    conv_first<<<dim3(1024), dim3(256), 0, stream>>>(preop, intra, buf0, w0, b0p);
    for (int i = 0; i < 100; ++i) {
        const float* src = (i & 1) ? buf1 : buf0;
        float* dst       = (i & 1) ? buf0 : buf1;
        conv_mid<<<dim3(512), dim3(256), 0, stream>>>(src, dst, wsp + i * 27, bsp + i);
    }
    conv_last<<<dim3(1024), dim3(256), 0, stream>>>(buf0, out, wX, bX);
}